// Round 1
// baseline (100.979 us; speedup 1.0000x reference)
//
#include <hip/hip_runtime.h>
#include <hip/hip_bf16.h>

#define B_DIM 64
#define I_DIM 16384
#define O_DIM 1024
#define K_BASIS 5
#define H_DIM 16
#define IK (I_DIM * K_BASIS)   // 81920

typedef __attribute__((ext_vector_type(8))) short short8;
typedef __attribute__((ext_vector_type(4))) short short4v;
typedef __attribute__((ext_vector_type(4))) float f32x4;

// ---------------------------------------------------------------------------
// Kernel 1: basis[b][i] = w2[i%5] . silu(x[b][i]*w1[i%5] + b1[i%5]) + b2[i%5]
// Output bf16, row-major [64][16384] (A-operand layout for the GEMM).
// ---------------------------------------------------------------------------
__global__ __launch_bounds__(256)
void basis_kernel(const float* __restrict__ x,
                  const float* __restrict__ w1,
                  const float* __restrict__ b1,
                  const float* __restrict__ w2,
                  const float* __restrict__ b2,
                  __hip_bfloat16* __restrict__ basis) {
    __shared__ float pw1[K_BASIS * H_DIM];
    __shared__ float pb1[K_BASIS * H_DIM];
    __shared__ float pw2[K_BASIS * H_DIM];
    __shared__ float pb2[K_BASIS];
    const int t = threadIdx.x;
    if (t < K_BASIS * H_DIM) {
        pw1[t] = w1[t];
        pb1[t] = b1[t];
        pw2[t] = w2[t];
        if (t < K_BASIS) pb2[t] = b2[t];
    }
    __syncthreads();

    // one thread -> 8 consecutive i of one batch row
    const int gid = blockIdx.x * 256 + t;        // 0 .. 131071
    const int i8 = gid % (I_DIM / 8);
    const int b  = gid / (I_DIM / 8);
    const int i0 = i8 * 8;

    const float4* xp = reinterpret_cast<const float4*>(x + (size_t)b * I_DIM + i0);
    float4 xa = xp[0];
    float4 xb = xp[1];
    float xs[8] = {xa.x, xa.y, xa.z, xa.w, xb.x, xb.y, xb.z, xb.w};

    __hip_bfloat16 res[8];
#pragma unroll
    for (int j = 0; j < 8; ++j) {
        const int idx = (i0 + j) % K_BASIS;
        const float xv = xs[j];
        float acc = 0.f;
#pragma unroll
        for (int h = 0; h < H_DIM; ++h) {
            float a = fmaf(xv, pw1[idx * H_DIM + h], pb1[idx * H_DIM + h]);
            float s = a / (1.f + __expf(-a));      // silu
            acc = fmaf(s, pw2[idx * H_DIM + h], acc);
        }
        res[j] = __float2bfloat16(acc + pb2[idx]);
    }
    *reinterpret_cast<short8*>(basis + (size_t)b * I_DIM + i0) =
        *reinterpret_cast<short8*>(res);
}

// ---------------------------------------------------------------------------
// Kernel 2: out[64,1024] = A' x B'^T  over ik = i*5+k (K = 81920)
//   A'[b][ik] = basis[b][ik/5]   (replicated 5x into LDS at stage time)
//   B'[o][ik] = W[o][ik]         (W is contiguous row-major [O][I*5])
// mfma_f32_16x16x32_bf16, f32 atomicAdd epilogue (out zeroed by memset).
// ---------------------------------------------------------------------------
#define NT 64          // o-tile per WG
#define KC 160         // ik per chunk (= 32 i, lcm(32,5))
#define NCHUNK 8       // chunks per WG -> 1280 ik per WG
#define LDA 168        // padded LDS row stride in elems (336 B = 21 x 16 B)

__global__ __launch_bounds__(256, 3)
void kan_gemm(const float* __restrict__ W,
              const __hip_bfloat16* __restrict__ basis,
              float* __restrict__ out) {
    __shared__ __hip_bfloat16 As[B_DIM * LDA];   // 21 KiB
    __shared__ __hip_bfloat16 Bs[NT * LDA];      // 21 KiB

    const int t    = threadIdx.x;
    const int lane = t & 63;
    const int wv   = t >> 6;
    const int o0   = blockIdx.x * NT;
    const int ik0  = blockIdx.y * (KC * NCHUNK);

    f32x4 acc[4] = {f32x4{0,0,0,0}, f32x4{0,0,0,0}, f32x4{0,0,0,0}, f32x4{0,0,0,0}};

    for (int c = 0; c < NCHUNK; ++c) {
        const int ikb = ik0 + c * KC;

        // ---- stage B: 64 o x 160 ik f32 -> bf16. 2560 float4, 10/thread ----
#pragma unroll
        for (int r = 0; r < 10; ++r) {
            const int idx = t + r * 256;          // 0..2559
            const int o   = idx / 40;             // 40 float4 per row
            const int e4  = idx - o * 40;
            const float4 v = *reinterpret_cast<const float4*>(
                W + (size_t)(o0 + o) * IK + ikb + e4 * 4);
            __hip_bfloat16 b4[4] = {__float2bfloat16(v.x), __float2bfloat16(v.y),
                                    __float2bfloat16(v.z), __float2bfloat16(v.w)};
            *reinterpret_cast<short4v*>(&Bs[o * LDA + e4 * 4]) =
                *reinterpret_cast<short4v*>(b4);
        }

        // ---- stage A: compact basis read + 5x replicate into LDS ----
        const int ib = ikb / K_BASIS;             // global i base (ikb % 5 == 0)
#pragma unroll
        for (int r = 0; r < 8; ++r) {
            const int item = t + r * 256;         // 0..2047
            const int row  = item >> 5;           // 0..63
            const int ic   = item & 31;
            const __hip_bfloat16 bv = basis[(size_t)row * I_DIM + ib + ic];
#pragma unroll
            for (int k = 0; k < K_BASIS; ++k)
                As[row * LDA + ic * K_BASIS + k] = bv;
        }
        __syncthreads();

        // ---- MFMA: 5 k-steps of 32, M=64 (4 frags), N=16 per wave ----
        const int col  = lane & 15;
        const int kgrp = lane >> 4;
#pragma unroll
        for (int ks = 0; ks < 5; ++ks) {
            const int koff = ks * 32 + kgrp * 8;
            const short8 bf = *reinterpret_cast<const short8*>(
                &Bs[(wv * 16 + col) * LDA + koff]);
#pragma unroll
            for (int m = 0; m < 4; ++m) {
                const short8 af = *reinterpret_cast<const short8*>(
                    &As[(m * 16 + col) * LDA + koff]);
                acc[m] = __builtin_amdgcn_mfma_f32_16x16x32_bf16(af, bf, acc[m], 0, 0, 0);
            }
        }
        __syncthreads();
    }

    // ---- epilogue: atomic accumulate the 64x64 partial tile ----
    const int col  = lane & 15;
    const int kgrp = lane >> 4;
    const int ocol = o0 + wv * 16 + col;
#pragma unroll
    for (int m = 0; m < 4; ++m) {
#pragma unroll
        for (int j = 0; j < 4; ++j) {
            const int brow = m * 16 + kgrp * 4 + j;
            atomicAdd(&out[(size_t)brow * O_DIM + ocol], acc[m][j]);
        }
    }
}

// ---------------------------------------------------------------------------
extern "C" void kernel_launch(void* const* d_in, const int* in_sizes, int n_in,
                              void* d_out, int out_size, void* d_ws, size_t ws_size,
                              hipStream_t stream) {
    const float* x  = (const float*)d_in[0];
    const float* w1 = (const float*)d_in[1];
    const float* b1 = (const float*)d_in[2];
    const float* w2 = (const float*)d_in[3];
    const float* b2 = (const float*)d_in[4];
    const float* W  = (const float*)d_in[5];
    float* out = (float*)d_out;
    __hip_bfloat16* basis = (__hip_bfloat16*)d_ws;   // 64*16384*2 = 2 MiB

    // out must be zero before atomic accumulation (harness poisons 0xAA).
    hipMemsetAsync(d_out, 0, (size_t)out_size * sizeof(float), stream);

    basis_kernel<<<dim3((B_DIM * I_DIM / 8) / 256), dim3(256), 0, stream>>>(
        x, w1, b1, w2, b2, basis);

    dim3 grid(O_DIM / NT, IK / (KC * NCHUNK));   // (16, 64)
    kan_gemm<<<grid, dim3(256), 0, stream>>>(W, basis, out);
}

// Round 2
// 88.515 us; speedup vs baseline: 1.1408x; 1.1408x over previous
//
#include <hip/hip_runtime.h>
#include <hip/hip_bf16.h>

#define B_DIM 64
#define I_DIM 16384
#define O_DIM 1024
#define K_BASIS 5
#define H_DIM 16
#define IK (I_DIM * K_BASIS)   // 81920

typedef __attribute__((ext_vector_type(8))) short short8;
typedef __attribute__((ext_vector_type(4))) short short4v;
typedef __attribute__((ext_vector_type(4))) float f32x4;

// ---------------------------------------------------------------------------
// Kernel 1: basis[b][i] = w2[i%5] . silu(x[b][i]*w1[i%5] + b1[i%5]) + b2[i%5]
// Output bf16, row-major [64][16384].
// ---------------------------------------------------------------------------
__global__ __launch_bounds__(256)
void basis_kernel(const float* __restrict__ x,
                  const float* __restrict__ w1,
                  const float* __restrict__ b1,
                  const float* __restrict__ w2,
                  const float* __restrict__ b2,
                  __hip_bfloat16* __restrict__ basis) {
    __shared__ float pw1[K_BASIS * H_DIM];
    __shared__ float pb1[K_BASIS * H_DIM];
    __shared__ float pw2[K_BASIS * H_DIM];
    __shared__ float pb2[K_BASIS];
    const int t = threadIdx.x;
    if (t < K_BASIS * H_DIM) {
        pw1[t] = w1[t];
        pb1[t] = b1[t];
        pw2[t] = w2[t];
        if (t < K_BASIS) pb2[t] = b2[t];
    }
    __syncthreads();

    const int gid = blockIdx.x * 256 + t;        // 0 .. 131071
    const int i8 = gid % (I_DIM / 8);
    const int b  = gid / (I_DIM / 8);
    const int i0 = i8 * 8;

    const float4* xp = reinterpret_cast<const float4*>(x + (size_t)b * I_DIM + i0);
    float4 xa = xp[0];
    float4 xb = xp[1];
    float xs[8] = {xa.x, xa.y, xa.z, xa.w, xb.x, xb.y, xb.z, xb.w};

    __hip_bfloat16 res[8];
#pragma unroll
    for (int j = 0; j < 8; ++j) {
        const int idx = (i0 + j) % K_BASIS;
        const float xv = xs[j];
        float acc = 0.f;
#pragma unroll
        for (int h = 0; h < H_DIM; ++h) {
            float a = fmaf(xv, pw1[idx * H_DIM + h], pb1[idx * H_DIM + h]);
            float s = a / (1.f + __expf(-a));      // silu
            acc = fmaf(s, pw2[idx * H_DIM + h], acc);
        }
        res[j] = __float2bfloat16(acc + pb2[idx]);
    }
    *reinterpret_cast<short8*>(basis + (size_t)b * I_DIM + i0) =
        *reinterpret_cast<short8*>(res);
}

// ---------------------------------------------------------------------------
// Kernel 2: out[64,1024] = basis[64,16384] @ Wsum[16384,1024]
// Wsum[o,i] = sum_k W[o,i*5+k], folded in REGISTERS during B-staging
// (20 consecutive f32 -> 4 i-group sums -> bf16). MFMA K = I only.
// Register double-buffer: issue chunk c+1 loads while MFMA on chunk c.
// ---------------------------------------------------------------------------
#define NT 64          // o-tile per WG
#define CI 32          // i per chunk (one 16x16x32 k-step)
#define NCHUNK 8       // chunks per WG -> 256 i per WG
#define LDB 40         // padded LDS row stride (80 B: bank rotation 20 -> 2-way max)

__global__ __launch_bounds__(256, 4)
void kan_gemm(const float* __restrict__ W,
              const __hip_bfloat16* __restrict__ basis,
              float* __restrict__ out) {
    __shared__ __hip_bfloat16 As[B_DIM * LDB];   // 5 KiB
    __shared__ __hip_bfloat16 Bs[NT * LDB];      // 5 KiB

    const int t    = threadIdx.x;
    const int lane = t & 63;
    const int wv   = t >> 6;
    const int o0   = blockIdx.x * NT;
    const int i00  = blockIdx.y * (CI * NCHUNK);

    // B-staging geometry: thread covers (oA, i4..i4+3) and (oA+32, i4..i4+3)
    const int oA = t >> 3;            // 0..31
    const int i4 = (t & 7) * 4;       // local i group base
    // A-staging geometry: 16B per thread
    const int arow = t >> 2;          // 0..63
    const int ac16 = (t & 3) * 8;     // elem offset within 32-i row

    const float* wp0 = W + (size_t)(o0 + oA) * IK;
    const float* wp1 = W + (size_t)(o0 + oA + 32) * IK;
    const __hip_bfloat16* ap = basis + (size_t)arow * I_DIM;

    float4 wr[10];
    short8 ar;

    auto issue = [&](int c) {
        const int ig = i00 + c * CI;
        const float4* p0 = reinterpret_cast<const float4*>(wp0 + (size_t)(ig + i4) * K_BASIS);
        const float4* p1 = reinterpret_cast<const float4*>(wp1 + (size_t)(ig + i4) * K_BASIS);
#pragma unroll
        for (int q = 0; q < 5; ++q) wr[q] = p0[q];
#pragma unroll
        for (int q = 0; q < 5; ++q) wr[5 + q] = p1[q];
        ar = *reinterpret_cast<const short8*>(ap + ig + ac16);
    };

    auto commit = [&]() {
#pragma unroll
        for (int r = 0; r < 2; ++r) {
            const float4 v0 = wr[r * 5 + 0], v1 = wr[r * 5 + 1], v2 = wr[r * 5 + 2],
                         v3 = wr[r * 5 + 3], v4 = wr[r * 5 + 4];
            float s0 = v0.x + v0.y + v0.z + v0.w + v1.x;
            float s1 = v1.y + v1.z + v1.w + v2.x + v2.y;
            float s2 = v2.z + v2.w + v3.x + v3.y + v3.z;
            float s3 = v3.w + v4.x + v4.y + v4.z + v4.w;
            __hip_bfloat16 b4[4] = {__float2bfloat16(s0), __float2bfloat16(s1),
                                    __float2bfloat16(s2), __float2bfloat16(s3)};
            *reinterpret_cast<short4v*>(&Bs[(oA + r * 32) * LDB + i4]) =
                *reinterpret_cast<short4v*>(b4);
        }
        *reinterpret_cast<short8*>(&As[arow * LDB + ac16]) = ar;
    };

    f32x4 acc[4] = {f32x4{0,0,0,0}, f32x4{0,0,0,0}, f32x4{0,0,0,0}, f32x4{0,0,0,0}};
    const int col  = lane & 15;
    const int kgrp = lane >> 4;
    const int koff = kgrp * 8;

    issue(0);
    for (int c = 0; c < NCHUNK; ++c) {
        commit();                      // vmcnt-waits chunk c's loads, fold + LDS write
        __syncthreads();               // tile visible
        if (c + 1 < NCHUNK) issue(c + 1);  // chunk c+1 loads fly over the MFMA phase
        const short8 bf = *reinterpret_cast<const short8*>(
            &Bs[(wv * 16 + col) * LDB + koff]);
#pragma unroll
        for (int m = 0; m < 4; ++m) {
            const short8 af = *reinterpret_cast<const short8*>(
                &As[(m * 16 + col) * LDB + koff]);
            acc[m] = __builtin_amdgcn_mfma_f32_16x16x32_bf16(af, bf, acc[m], 0, 0, 0);
        }
        __syncthreads();               // MFMA done before next commit overwrites
    }

    // ---- epilogue: atomic accumulate the 64x64 partial tile ----
    const int ocol = o0 + wv * 16 + col;
#pragma unroll
    for (int m = 0; m < 4; ++m) {
#pragma unroll
        for (int j = 0; j < 4; ++j) {
            const int brow = m * 16 + kgrp * 4 + j;
            atomicAdd(&out[(size_t)brow * O_DIM + ocol], acc[m][j]);
        }
    }
}

// ---------------------------------------------------------------------------
extern "C" void kernel_launch(void* const* d_in, const int* in_sizes, int n_in,
                              void* d_out, int out_size, void* d_ws, size_t ws_size,
                              hipStream_t stream) {
    const float* x  = (const float*)d_in[0];
    const float* w1 = (const float*)d_in[1];
    const float* b1 = (const float*)d_in[2];
    const float* w2 = (const float*)d_in[3];
    const float* b2 = (const float*)d_in[4];
    const float* W  = (const float*)d_in[5];
    float* out = (float*)d_out;
    __hip_bfloat16* basis = (__hip_bfloat16*)d_ws;   // 64*16384*2 = 2 MiB

    hipMemsetAsync(d_out, 0, (size_t)out_size * sizeof(float), stream);

    basis_kernel<<<dim3((B_DIM * I_DIM / 8) / 256), dim3(256), 0, stream>>>(
        x, w1, b1, w2, b2, basis);

    dim3 grid(O_DIM / NT, I_DIM / (CI * NCHUNK));   // (16, 64)
    kan_gemm<<<grid, dim3(256), 0, stream>>>(W, basis, out);
}